// Round 10
// baseline (685.865 us; speedup 1.0000x reference)
//
#include <hip/hip_runtime.h>
#include <stdint.h>

// Problem constants (fixed by setup_inputs)
constexpr int B_SZ     = 128;
constexpr int IN_CAPS  = 1152;
constexpr int OUT_CAPS = 32;
constexpr int OUT_D    = 16;
constexpr int ITERS    = 3;

constexpr int THREADS  = 1024;              // 16 waves
constexpr int NW       = THREADS / 64;      // 16
constexpr int G        = 2;                 // batches per block
constexpr int TILE_R   = 128;               // i-rows per W tile
constexpr int NTILE    = IN_CAPS / TILE_R;  // 9
constexpr int ROW_F    = 128;               // f32 per W row (32 x 16B chunks)

// async global->LDS: 16B/lane, LDS dest = wave-uniform base + lane*16,
// global source per-lane.
typedef const uint32_t __attribute__((address_space(1)))* gptr_t;
typedef uint32_t       __attribute__((address_space(3)))* lptr_t;
__device__ __forceinline__ void async_copy16(const float* g, float* l) {
    __builtin_amdgcn_global_load_lds((gptr_t)g, (lptr_t)l, 16, 0, 0);
}

// R5 structure (158us, best measured: coalesced glds staging, reg-resident
// uh[9][4], dbuf 2x64KB) + T3/T4 counted-vmcnt sync. R5-R9 showed a constant
// ~5K cyc per barrier-phase: __syncthreads' implicit s_waitcnt vmcnt(0)
// drains the staging pipe every tile and 1 block/CU has nothing to cover the
// refill. Replace with: issue stage(T+1) -> s_waitcnt vmcnt(#just-issued)
// (oldest = tile T's loads complete; T+1's stay IN FLIGHT across the barrier)
// -> raw s_barrier -> sched_barrier(0) -> COMP(T) -> raw s_barrier (protects
// buf[T&1] from stage(T+2); drain-free). To keep the compiler from inserting
// its own conservative vmcnt(0) (it can't see through the asm), u is staged
// through LDS as well -- the K-loop has NO VGPR-bound VMEM.
__global__ __launch_bounds__(THREADS) void caps_route(
    const float* __restrict__ u,   // [B, IN_CAPS, 8]
    const float* __restrict__ w,   // [IN_CAPS, OUT_CAPS, 8, 16]
    float* __restrict__ out)       // [B, OUT_CAPS, OUT_D]
{
    __shared__ __align__(16) float wt[2][TILE_R * ROW_F];  // 2 x 64 KB
    __shared__ __align__(16) float ut[2][G * TILE_R * 8];  // 2 x 8 KB
    __shared__ float red_es[NW * 8];                       // esum partials
    __shared__ __align__(16) float red_m[NW * 8 * 4];      // s[4] partials

    // Bijective XCD swizzle (2048 % 8 == 0): j-major ids -> each XCD's L2
    // holds 4 j-columns (2.3 MB < 4 MB) -> W re-reads are L2 hits.
    const int nwg = gridDim.x;               // 2048
    const int bid = blockIdx.x;
    const int wid = (bid & 7) * (nwg >> 3) + (bid >> 3);
    const int j   = wid >> 6;                // 0..31
    const int b0  = (wid & 63) * G;          // 0..126 step 2

    const int tid  = threadIdx.x;
    const int lane = tid & 63;
    const int wv   = tid >> 6;               // wave 0..15
    const int bl   = tid & 1;                // batch within pair
    const int mq   = (tid >> 1) & 3;         // m-quarter
    const int ir   = tid >> 3;               // i-row in tile, 0..127

    // R5's measured-good swizzle (both sides of the involution)
    const int mir = (ir & 7) | ((ir & 3) << 3);
    int foff[8];
    #pragma unroll
    for (int n = 0; n < 8; ++n) foff[n] = (((4 * n + mq) ^ mir) << 2);

    const float* wj = w + (size_t)j * 128;   // + i*4096 + chunk*4

    float uh[NTILE][4];                      // 36 VGPRs, literal indexing

    // ---- staging: W = 4 issues/wave; u = 1 issue on waves 0-7 ----
    #define STAGE_W(NB, T)                                                    \
    do {                                                                      \
        _Pragma("unroll")                                                     \
        for (int q = 0; q < 4; ++q) {                                         \
            const int Lb   = (wv * 4 + q) * 64;                               \
            const int L    = Lb + lane;                                       \
            const int row  = L >> 5;                                          \
            const int slot = L & 31;                                          \
            const int c    = slot ^ ((row & 7) | ((row & 3) << 3));           \
            const float* gsrc = wj +                                          \
                ((size_t)(((T) * TILE_R + row) * OUT_CAPS + j) * 0 +          \
                 (size_t)((T) * TILE_R + row) * 4096 + c * 4);                \
            async_copy16(gsrc, &wt[(NB)][Lb * 4]);                            \
        }                                                                     \
    } while (0)

    #define STAGE_U(NB, T)                                                    \
    do {                                                                      \
        if (wv < 8) {                                                         \
            const int ubl = wv >> 2;       /* batch 0/1 */                    \
            const int q   = wv & 3;        /* row quarter */                  \
            const float* gsrc = u +                                           \
                ((size_t)(b0 + ubl) * IN_CAPS + (T) * TILE_R + q * 32) * 8 +  \
                lane * 4;                                                     \
            async_copy16(gsrc, &ut[(NB)][ubl * 1024 + q * 256]);              \
        }                                                                     \
    } while (0)

    // ---- compute uh[T][0..3] for my (b, i-row, m-quarter) ----
    #define COMP(NB, T)                                                       \
    do {                                                                      \
        const float* urow = &ut[(NB)][bl * 1024 + ir * 8];                    \
        const float4 u0 = *reinterpret_cast<const float4*>(urow);             \
        const float4 u1 = *reinterpret_cast<const float4*>(urow + 4);         \
        const float uc[8] = {u0.x, u0.y, u0.z, u0.w, u1.x, u1.y, u1.z, u1.w}; \
        const float* trow = &wt[(NB)][ir * ROW_F];                            \
        float a0 = 0.f, a1 = 0.f, a2 = 0.f, a3 = 0.f;                         \
        _Pragma("unroll")                                                     \
        for (int n = 0; n < 8; ++n) {                                         \
            const float4 w4 = *reinterpret_cast<const float4*>(trow + foff[n]); \
            a0 = fmaf(uc[n], w4.x, a0);                                       \
            a1 = fmaf(uc[n], w4.y, a1);                                       \
            a2 = fmaf(uc[n], w4.z, a2);                                       \
            a3 = fmaf(uc[n], w4.w, a3);                                       \
        }                                                                     \
        uh[(T)][0] = a0; uh[(T)][1] = a1;                                     \
        uh[(T)][2] = a2; uh[(T)][3] = a3;                                     \
    } while (0)

    // ---- tile step with counted vmcnt (T3/T4) ----
    // Per-wave issues/tile: waves 0-7: 5 (4 W + 1 u); waves 8-15: 4.
    // After issuing T+1: outstanding = 2N -> wait vmcnt(N) completes tile T.
    #define STEP(T)                                                           \
    do {                                                                      \
        if ((T) + 1 < NTILE) {                                                \
            STAGE_W(((T) + 1) & 1, (T) + 1);                                  \
            STAGE_U(((T) + 1) & 1, (T) + 1);                                  \
            if (wv < 8) asm volatile("s_waitcnt vmcnt(5)" ::: "memory");      \
            else        asm volatile("s_waitcnt vmcnt(4)" ::: "memory");      \
        } else {                                                              \
            asm volatile("s_waitcnt vmcnt(0)" ::: "memory");                  \
        }                                                                     \
        __builtin_amdgcn_s_barrier();        /* everyone's tile T in LDS */   \
        __builtin_amdgcn_sched_barrier(0);   /* rule 18: pin reads below */   \
        COMP((T) & 1, T);                                                     \
        __builtin_amdgcn_s_barrier();        /* reads done before T+2 lands */\
    } while (0)

    // ---- prologue + 9 steps ----
    STAGE_W(0, 0);
    STAGE_U(0, 0);
    STEP(0); STEP(1); STEP(2); STEP(3); STEP(4);
    STEP(5); STEP(6); STEP(7); STEP(8);
    #undef STEP
    #undef COMP
    #undef STAGE_U
    #undef STAGE_W

    // ================= routing iterations (R5 verbatim) =================
    // exp-domain logits: e[r] = exp(b[r]); iter 0 is exp(0) = 1 exactly.
    float e[NTILE];
    #pragma unroll
    for (int r = 0; r < NTILE; ++r) e[r] = 1.0f;
    float vv[4];
    const int grp = lane & 7;                // (mq<<1)|bl

    for (int it = 0; it < ITERS; ++it) {
        float esum = 0.0f;
        #pragma unroll
        for (int r = 0; r < NTILE; ++r) esum += e[r];
        esum += __shfl_xor(esum, 8);
        esum += __shfl_xor(esum, 16);
        esum += __shfl_xor(esum, 32);

        float sp0 = 0.f, sp1 = 0.f, sp2 = 0.f, sp3 = 0.f;
        #pragma unroll
        for (int r = 0; r < NTILE; ++r) {
            sp0 = fmaf(e[r], uh[r][0], sp0);
            sp1 = fmaf(e[r], uh[r][1], sp1);
            sp2 = fmaf(e[r], uh[r][2], sp2);
            sp3 = fmaf(e[r], uh[r][3], sp3);
        }
        sp0 += __shfl_xor(sp0, 8);  sp1 += __shfl_xor(sp1, 8);
        sp2 += __shfl_xor(sp2, 8);  sp3 += __shfl_xor(sp3, 8);
        sp0 += __shfl_xor(sp0, 16); sp1 += __shfl_xor(sp1, 16);
        sp2 += __shfl_xor(sp2, 16); sp3 += __shfl_xor(sp3, 16);
        sp0 += __shfl_xor(sp0, 32); sp1 += __shfl_xor(sp1, 32);
        sp2 += __shfl_xor(sp2, 32); sp3 += __shfl_xor(sp3, 32);

        if (lane < 8) {   // one rep per (bl,mq) group
            red_es[wv * 8 + lane] = esum;
            *reinterpret_cast<float4*>(&red_m[(wv * 8 + lane) * 4]) =
                make_float4(sp0, sp1, sp2, sp3);
        }
        __syncthreads();
        float gsum = 0.0f;
        float sa0 = 0.f, sa1 = 0.f, sa2 = 0.f, sa3 = 0.f;
        #pragma unroll
        for (int q = 0; q < NW; ++q) {
            gsum += red_es[q * 8 + grp];
            const float4 rm =
                *reinterpret_cast<const float4*>(&red_m[(q * 8 + grp) * 4]);
            sa0 += rm.x; sa1 += rm.y; sa2 += rm.z; sa3 += rm.w;
        }
        __syncthreads();   // reads done before next iteration's writes

        const float cinv = 1.0f / gsum;
        vv[0] = sa0 * cinv; vv[1] = sa1 * cinv;
        vv[2] = sa2 * cinv; vv[3] = sa3 * cinv;
        float s2 = fmaf(vv[0], vv[0], fmaf(vv[1], vv[1],
                   fmaf(vv[2], vv[2], vv[3] * vv[3])));
        s2 += __shfl_xor(s2, 2);   // combine the 4 m-quarters (same bl)
        s2 += __shfl_xor(s2, 4);
        const float scale = (s2 / (1.0f + s2)) * rsqrtf(s2 + 1e-8f);
        vv[0] *= scale; vv[1] *= scale; vv[2] *= scale; vv[3] *= scale;

        // logit update: a = sum_m v[m]*uh[i][m]; combine mq via masks 2,4
        if (it < ITERS - 1) {
            #pragma unroll
            for (int r = 0; r < NTILE; ++r) {
                float a = fmaf(vv[0], uh[r][0], fmaf(vv[1], uh[r][1],
                          fmaf(vv[2], uh[r][2], vv[3] * uh[r][3])));
                a += __shfl_xor(a, 2);
                a += __shfl_xor(a, 4);
                e[r] *= __expf(a);
            }
        }
    }

    // ---- write v[b0+bl, j, mq*4 .. mq*4+3] ----
    if (tid < 8) {
        float4* op = reinterpret_cast<float4*>(
            out + ((size_t)(b0 + bl) * OUT_CAPS + j) * OUT_D + mq * 4);
        *op = make_float4(vv[0], vv[1], vv[2], vv[3]);
    }
}

extern "C" void kernel_launch(void* const* d_in, const int* in_sizes, int n_in,
                              void* d_out, int out_size, void* d_ws, size_t ws_size,
                              hipStream_t stream) {
    const float* u = (const float*)d_in[0];   // [128, 1152, 8]
    const float* w = (const float*)d_in[1];   // [1152, 32, 8, 16]
    float* out     = (float*)d_out;           // [128, 32, 16]
    (void)in_sizes; (void)n_in; (void)out_size; (void)d_ws; (void)ws_size;

    dim3 grid(OUT_CAPS * (B_SZ / G));   // 32 j x 64 batch-pairs = 2048 blocks
    dim3 block(THREADS);                // 1024 threads = 16 waves
    hipLaunchKernelGGL(caps_route, grid, block, 0, stream, u, w, out);
}

// Round 11
// 673.081 us; speedup vs baseline: 1.0190x; 1.0190x over previous
//
#include <hip/hip_runtime.h>
#include <stdint.h>

// Problem constants (fixed by setup_inputs)
constexpr int B_SZ     = 128;
constexpr int IN_CAPS  = 1152;
constexpr int OUT_CAPS = 32;
constexpr int OUT_D    = 16;
constexpr int ITERS    = 3;

constexpr int THREADS  = 1024;              // 16 waves
constexpr int NW       = THREADS / 64;      // 16
constexpr int G        = 2;                 // batches per block
constexpr int TILE_R   = 128;               // i-rows per W tile
constexpr int NTILE    = IN_CAPS / TILE_R;  // 9
constexpr int ROW_F    = 128;               // f32 per W row (32 x 16B chunks)

// async global->LDS: 16B/lane, LDS dest = wave-uniform base + lane*16,
// global source per-lane.
typedef const uint32_t __attribute__((address_space(1)))* gptr_t;
typedef uint32_t       __attribute__((address_space(3)))* lptr_t;
__device__ __forceinline__ void async_copy16(const float* g, float* l) {
    __builtin_amdgcn_global_load_lds((gptr_t)g, (lptr_t)l, 16, 0, 0);
}

// R10's counted-vmcnt schedule, with the register budget fixed.
// R10 lesson: __launch_bounds__(1024) alone -> allocator targets 8 waves/EU
// -> 64-VGPR cap -> uh[9][4] spilled (WRITE_SIZE 1.6 GB). 150 KB LDS forces
// 1 block/CU = 16 waves = 4 waves/EU regardless, so declare it:
// __launch_bounds__(1024, 4) -> 128-VGPR cap (R8's (512,2)=112-VGPR precedent
// proves the 2nd arg opens the budget). Peak live here ~100 -> zero spill.
//
// Schedule (T3/T4): issue stage(T+1) -> s_waitcnt vmcnt(#just-issued)
// (= tile T's loads complete; T+1's stay IN FLIGHT across the barrier) ->
// raw s_barrier -> sched_barrier(0) -> COMP(T) -> raw s_barrier. The K-loop
// has NO VGPR-bound VMEM (u staged through LDS too), so the compiler has no
// reason to insert its own vmcnt waits.
__global__ __launch_bounds__(THREADS, 4) void caps_route(
    const float* __restrict__ u,   // [B, IN_CAPS, 8]
    const float* __restrict__ w,   // [IN_CAPS, OUT_CAPS, 8, 16]
    float* __restrict__ out)       // [B, OUT_CAPS, OUT_D]
{
    __shared__ __align__(16) float wt[2][TILE_R * ROW_F];  // 2 x 64 KB
    __shared__ __align__(16) float ut[2][G * TILE_R * 8];  // 2 x 8 KB
    __shared__ float red_es[NW * 8];                       // esum partials
    __shared__ __align__(16) float red_m[NW * 8 * 4];      // s[4] partials

    // Bijective XCD swizzle (2048 % 8 == 0): j-major ids -> each XCD's L2
    // holds 4 j-columns (2.3 MB < 4 MB) -> W re-reads are L2 hits.
    const int nwg = gridDim.x;               // 2048
    const int bid = blockIdx.x;
    const int wid = (bid & 7) * (nwg >> 3) + (bid >> 3);
    const int j   = wid >> 6;                // 0..31
    const int b0  = (wid & 63) * G;          // 0..126 step 2

    const int tid  = threadIdx.x;
    const int lane = tid & 63;
    const int wv   = tid >> 6;               // wave 0..15
    const int bl   = tid & 1;                // batch within pair
    const int mq   = (tid >> 1) & 3;         // m-quarter
    const int ir   = tid >> 3;               // i-row in tile, 0..127

    // R5's measured-good swizzle (both sides of the involution)
    const int mir = (ir & 7) | ((ir & 3) << 3);
    int foff[8];
    #pragma unroll
    for (int n = 0; n < 8; ++n) foff[n] = (((4 * n + mq) ^ mir) << 2);

    const float* wj = w + (size_t)j * 128;   // + i*4096 + chunk*4

    float uh[NTILE][4];                      // 36 VGPRs, literal indexing

    // ---- staging: W = 4 issues/wave; u = 1 issue on waves 0-7 ----
    #define STAGE_W(NB, T)                                                    \
    do {                                                                      \
        _Pragma("unroll")                                                     \
        for (int q = 0; q < 4; ++q) {                                         \
            const int Lb   = (wv * 4 + q) * 64;                               \
            const int L    = Lb + lane;                                       \
            const int row  = L >> 5;                                          \
            const int slot = L & 31;                                          \
            const int c    = slot ^ ((row & 7) | ((row & 3) << 3));           \
            const float* gsrc = wj +                                          \
                (size_t)((T) * TILE_R + row) * 4096 + c * 4;                  \
            async_copy16(gsrc, &wt[(NB)][Lb * 4]);                            \
        }                                                                     \
    } while (0)

    #define STAGE_U(NB, T)                                                    \
    do {                                                                      \
        if (wv < 8) {                                                         \
            const int ubl = wv >> 2;       /* batch 0/1 */                    \
            const int q   = wv & 3;        /* row quarter */                  \
            const float* gsrc = u +                                           \
                ((size_t)(b0 + ubl) * IN_CAPS + (T) * TILE_R + q * 32) * 8 +  \
                lane * 4;                                                     \
            async_copy16(gsrc, &ut[(NB)][ubl * 1024 + q * 256]);              \
        }                                                                     \
    } while (0)

    // ---- compute uh[T][0..3] for my (b, i-row, m-quarter) ----
    #define COMP(NB, T)                                                       \
    do {                                                                      \
        const float* urow = &ut[(NB)][bl * 1024 + ir * 8];                    \
        const float4 u0 = *reinterpret_cast<const float4*>(urow);             \
        const float4 u1 = *reinterpret_cast<const float4*>(urow + 4);         \
        const float uc[8] = {u0.x, u0.y, u0.z, u0.w, u1.x, u1.y, u1.z, u1.w}; \
        const float* trow = &wt[(NB)][ir * ROW_F];                            \
        float a0 = 0.f, a1 = 0.f, a2 = 0.f, a3 = 0.f;                         \
        _Pragma("unroll")                                                     \
        for (int n = 0; n < 8; ++n) {                                         \
            const float4 w4 = *reinterpret_cast<const float4*>(trow + foff[n]); \
            a0 = fmaf(uc[n], w4.x, a0);                                       \
            a1 = fmaf(uc[n], w4.y, a1);                                       \
            a2 = fmaf(uc[n], w4.z, a2);                                       \
            a3 = fmaf(uc[n], w4.w, a3);                                       \
        }                                                                     \
        uh[(T)][0] = a0; uh[(T)][1] = a1;                                     \
        uh[(T)][2] = a2; uh[(T)][3] = a3;                                     \
    } while (0)

    // ---- tile step with counted vmcnt (T3/T4) ----
    // Per-wave issues/tile: waves 0-7: 5 (4 W + 1 u); waves 8-15: 4.
    // After issuing T+1: outstanding = 2N -> wait vmcnt(N) completes tile T,
    // leaves tile T+1's loads in flight across the barrier.
    #define STEP(T)                                                           \
    do {                                                                      \
        if ((T) + 1 < NTILE) {                                                \
            STAGE_W(((T) + 1) & 1, (T) + 1);                                  \
            STAGE_U(((T) + 1) & 1, (T) + 1);                                  \
            if (wv < 8) asm volatile("s_waitcnt vmcnt(5)" ::: "memory");      \
            else        asm volatile("s_waitcnt vmcnt(4)" ::: "memory");      \
        } else {                                                              \
            asm volatile("s_waitcnt vmcnt(0)" ::: "memory");                  \
        }                                                                     \
        __builtin_amdgcn_s_barrier();        /* everyone's tile T in LDS */   \
        __builtin_amdgcn_sched_barrier(0);   /* rule 18: pin reads below */   \
        COMP((T) & 1, T);                                                     \
        __builtin_amdgcn_s_barrier();        /* reads done before T+2 lands */\
    } while (0)

    // ---- prologue + 9 steps ----
    STAGE_W(0, 0);
    STAGE_U(0, 0);
    STEP(0); STEP(1); STEP(2); STEP(3); STEP(4);
    STEP(5); STEP(6); STEP(7); STEP(8);
    #undef STEP
    #undef COMP
    #undef STAGE_U
    #undef STAGE_W

    // ================= routing iterations (R5 verbatim) =================
    // exp-domain logits: e[r] = exp(b[r]); iter 0 is exp(0) = 1 exactly.
    float e[NTILE];
    #pragma unroll
    for (int r = 0; r < NTILE; ++r) e[r] = 1.0f;
    float vv[4];
    const int grp = lane & 7;                // (mq<<1)|bl

    for (int it = 0; it < ITERS; ++it) {
        float esum = 0.0f;
        #pragma unroll
        for (int r = 0; r < NTILE; ++r) esum += e[r];
        esum += __shfl_xor(esum, 8);
        esum += __shfl_xor(esum, 16);
        esum += __shfl_xor(esum, 32);

        float sp0 = 0.f, sp1 = 0.f, sp2 = 0.f, sp3 = 0.f;
        #pragma unroll
        for (int r = 0; r < NTILE; ++r) {
            sp0 = fmaf(e[r], uh[r][0], sp0);
            sp1 = fmaf(e[r], uh[r][1], sp1);
            sp2 = fmaf(e[r], uh[r][2], sp2);
            sp3 = fmaf(e[r], uh[r][3], sp3);
        }
        sp0 += __shfl_xor(sp0, 8);  sp1 += __shfl_xor(sp1, 8);
        sp2 += __shfl_xor(sp2, 8);  sp3 += __shfl_xor(sp3, 8);
        sp0 += __shfl_xor(sp0, 16); sp1 += __shfl_xor(sp1, 16);
        sp2 += __shfl_xor(sp2, 16); sp3 += __shfl_xor(sp3, 16);
        sp0 += __shfl_xor(sp0, 32); sp1 += __shfl_xor(sp1, 32);
        sp2 += __shfl_xor(sp2, 32); sp3 += __shfl_xor(sp3, 32);

        if (lane < 8) {   // one rep per (bl,mq) group
            red_es[wv * 8 + lane] = esum;
            *reinterpret_cast<float4*>(&red_m[(wv * 8 + lane) * 4]) =
                make_float4(sp0, sp1, sp2, sp3);
        }
        __syncthreads();
        float gsum = 0.0f;
        float sa0 = 0.f, sa1 = 0.f, sa2 = 0.f, sa3 = 0.f;
        #pragma unroll
        for (int q = 0; q < NW; ++q) {
            gsum += red_es[q * 8 + grp];
            const float4 rm =
                *reinterpret_cast<const float4*>(&red_m[(q * 8 + grp) * 4]);
            sa0 += rm.x; sa1 += rm.y; sa2 += rm.z; sa3 += rm.w;
        }
        __syncthreads();   // reads done before next iteration's writes

        const float cinv = 1.0f / gsum;
        vv[0] = sa0 * cinv; vv[1] = sa1 * cinv;
        vv[2] = sa2 * cinv; vv[3] = sa3 * cinv;
        float s2 = fmaf(vv[0], vv[0], fmaf(vv[1], vv[1],
                   fmaf(vv[2], vv[2], vv[3] * vv[3])));
        s2 += __shfl_xor(s2, 2);   // combine the 4 m-quarters (same bl)
        s2 += __shfl_xor(s2, 4);
        const float scale = (s2 / (1.0f + s2)) * rsqrtf(s2 + 1e-8f);
        vv[0] *= scale; vv[1] *= scale; vv[2] *= scale; vv[3] *= scale;

        // logit update: a = sum_m v[m]*uh[i][m]; combine mq via masks 2,4
        if (it < ITERS - 1) {
            #pragma unroll
            for (int r = 0; r < NTILE; ++r) {
                float a = fmaf(vv[0], uh[r][0], fmaf(vv[1], uh[r][1],
                          fmaf(vv[2], uh[r][2], vv[3] * uh[r][3])));
                a += __shfl_xor(a, 2);
                a += __shfl_xor(a, 4);
                e[r] *= __expf(a);
            }
        }
    }

    // ---- write v[b0+bl, j, mq*4 .. mq*4+3] ----
    if (tid < 8) {
        float4* op = reinterpret_cast<float4*>(
            out + ((size_t)(b0 + bl) * OUT_CAPS + j) * OUT_D + mq * 4);
        *op = make_float4(vv[0], vv[1], vv[2], vv[3]);
    }
}

extern "C" void kernel_launch(void* const* d_in, const int* in_sizes, int n_in,
                              void* d_out, int out_size, void* d_ws, size_t ws_size,
                              hipStream_t stream) {
    const float* u = (const float*)d_in[0];   // [128, 1152, 8]
    const float* w = (const float*)d_in[1];   // [1152, 32, 8, 16]
    float* out     = (float*)d_out;           // [128, 32, 16]
    (void)in_sizes; (void)n_in; (void)out_size; (void)d_ws; (void)ws_size;

    dim3 grid(OUT_CAPS * (B_SZ / G));   // 32 j x 64 batch-pairs = 2048 blocks
    dim3 block(THREADS);                // 1024 threads = 16 waves
    hipLaunchKernelGGL(caps_route, grid, block, 0, stream, u, w, out);
}

// Round 12
// 166.664 us; speedup vs baseline: 4.1153x; 4.0385x over previous
//
#include <hip/hip_runtime.h>
#include <stdint.h>

// Problem constants (fixed by setup_inputs)
constexpr int B_SZ     = 128;
constexpr int IN_CAPS  = 1152;
constexpr int OUT_CAPS = 32;
constexpr int OUT_D    = 16;
constexpr int ITERS    = 3;

constexpr int THREADS  = 512;               // 8 waves
constexpr int NW       = THREADS / 64;      // 8
constexpr int G        = 2;                 // batches per block
constexpr int TILE_R   = 64;                // i-rows per W tile
constexpr int NTILE    = IN_CAPS / TILE_R;  // 18
constexpr int ROW_F    = 128;               // f32 per W row (32 x 16B chunks)

// async global->LDS: 16B/lane, LDS dest = wave-uniform base + lane*16,
// global source per-lane.
typedef const uint32_t __attribute__((address_space(1)))* gptr_t;
typedef uint32_t       __attribute__((address_space(3)))* lptr_t;
__device__ __forceinline__ void async_copy16(const float* g, float* l) {
    __builtin_amdgcn_global_load_lds((gptr_t)g, (lptr_t)l, 16, 0, 0);
}

// R5's proven pipeline (158us; coalesced glds staging, dbuf W tiles, one
// barrier/step, reg-resident uh, measured swizzle) re-cut for 512 threads.
//
// WHY 512: cross-round register-budget evidence -- every 1024-thread variant
// (R5/R6/R7/R10/R11) was capped at <=64 VGPRs regardless of launch_bounds /
// waves_per_eu attributes; only 512-thread __launch_bounds__(512,2) opened
// the budget (R8: 112 VGPRs, zero spill). uh[18][4]=72 + e[18] + addressing
// ~= 105 live regs fits that budget; at 1024 threads it spilled 1.6 GB.
//
// WHY it should beat R5: LDS = 73 KB -> 2 blocks/CU. The per-step
// __syncthreads vmcnt(0) drain and the routing phase now overlap with the
// partner block (R5 ran 1 block/CU and ate every drain exposed).
__global__ __launch_bounds__(THREADS, 2) void caps_route(
    const float* __restrict__ u,   // [B, IN_CAPS, 8]
    const float* __restrict__ w,   // [IN_CAPS, OUT_CAPS, 8, 16]
    float* __restrict__ out)       // [B, OUT_CAPS, OUT_D]
{
    __shared__ __align__(16) float wt[2][TILE_R * ROW_F];  // 2 x 32 KB
    __shared__ float red_es[NW * 8];                       // esum partials
    __shared__ __align__(16) float red_m[NW * 8 * 4];      // s[4] partials

    // Bijective XCD swizzle (2048 % 8 == 0): j-major ids -> each XCD's L2
    // holds 4 j-columns (2.3 MB < 4 MB) -> W re-reads are L2 hits.
    const int nwg = gridDim.x;               // 2048
    const int bid = blockIdx.x;
    const int wid = (bid & 7) * (nwg >> 3) + (bid >> 3);
    const int j   = wid >> 6;                // 0..31
    const int b0  = (wid & 63) * G;          // 0..126 step 2

    const int tid  = threadIdx.x;
    const int lane = tid & 63;
    const int wv   = tid >> 6;               // wave 0..7
    const int bl   = tid & 1;                // batch within pair
    const int mq   = (tid >> 1) & 3;         // m-quarter
    const int ir   = tid >> 3;               // i-row in tile, 0..63

    // R5's measured-good swizzle (both sides of the involution)
    const int mir = (ir & 7) | ((ir & 3) << 3);
    int foff[8];
    #pragma unroll
    for (int n = 0; n < 8; ++n) foff[n] = (((4 * n + mq) ^ mir) << 2);

    const float* wj = w + (size_t)j * 128;   // + i*4096 + chunk*4
    const float* ub = u + (size_t)(b0 + bl) * IN_CAPS * 8;

    float uh[NTILE][4];                      // 72 VGPRs, literal indexing
    float4 uA0, uA1, uB0, uB1;               // u[b, i, :] cur/next tile

    // stage W tile T (64 rows x 512 B = 32 KB) into buffer NB:
    // 8 waves x 4 issues x 1 KB, linear LDS dest, pre-permuted global source
    #define STAGE(NB, T)                                                      \
    do {                                                                      \
        _Pragma("unroll")                                                     \
        for (int q = 0; q < 4; ++q) {                                         \
            const int Lb   = (wv * 4 + q) * 64;                               \
            const int L    = Lb + lane;                                       \
            const int row  = L >> 5;            /* 0..63 */                   \
            const int slot = L & 31;                                          \
            const int c    = slot ^ ((row & 7) | ((row & 3) << 3));           \
            const float* gsrc = wj +                                          \
                (size_t)((T) * TILE_R + row) * 4096 + c * 4;                  \
            async_copy16(gsrc, &wt[(NB)][Lb * 4]);                            \
        }                                                                     \
    } while (0)

    #define ULOAD(T, U0, U1)                                                  \
    do {                                                                      \
        const float* up = ub + (size_t)((T) * TILE_R + ir) * 8;               \
        U0 = *reinterpret_cast<const float4*>(up);                            \
        U1 = *reinterpret_cast<const float4*>(up + 4);                        \
    } while (0)

    // compute uh[T][0..3] for my (b, i-row, m-quarter) from buffer NB
    #define COMP(NB, T, U0, U1)                                               \
    do {                                                                      \
        const float uc[8] = {U0.x, U0.y, U0.z, U0.w, U1.x, U1.y, U1.z, U1.w}; \
        const float* trow = &wt[(NB)][ir * ROW_F];                            \
        float a0 = 0.f, a1 = 0.f, a2 = 0.f, a3 = 0.f;                         \
        _Pragma("unroll")                                                     \
        for (int n = 0; n < 8; ++n) {                                         \
            const float4 w4 = *reinterpret_cast<const float4*>(trow + foff[n]); \
            a0 = fmaf(uc[n], w4.x, a0);                                       \
            a1 = fmaf(uc[n], w4.y, a1);                                       \
            a2 = fmaf(uc[n], w4.z, a2);                                       \
            a3 = fmaf(uc[n], w4.w, a3);                                       \
        }                                                                     \
        uh[(T)][0] = a0; uh[(T)][1] = a1;                                     \
        uh[(T)][2] = a2; uh[(T)][3] = a3;                                     \
    } while (0)

    // step T: stage(T+1) into the other buffer + prefetch u(T+1) to regs,
    // compute tile T, one barrier. Stage(T+1) writes buf[(T+1)&1] while
    // COMP(T) reads buf[T&1] (disjoint); the end barrier fences both the
    // vmcnt drain and the next step's overwrite of buf[T&1]'s partner.
    #define STEP(T, UC0, UC1, UN0, UN1)                                       \
    do {                                                                      \
        if ((T) + 1 < NTILE) {                                                \
            STAGE(((T) + 1) & 1, (T) + 1);                                    \
            ULOAD((T) + 1, UN0, UN1);                                         \
        }                                                                     \
        COMP((T) & 1, T, UC0, UC1);                                           \
        __syncthreads();                                                      \
    } while (0)

    // ---- prologue + 18 steps ----
    STAGE(0, 0);
    ULOAD(0, uA0, uA1);
    __syncthreads();
    STEP(0,  uA0, uA1, uB0, uB1);  STEP(1,  uB0, uB1, uA0, uA1);
    STEP(2,  uA0, uA1, uB0, uB1);  STEP(3,  uB0, uB1, uA0, uA1);
    STEP(4,  uA0, uA1, uB0, uB1);  STEP(5,  uB0, uB1, uA0, uA1);
    STEP(6,  uA0, uA1, uB0, uB1);  STEP(7,  uB0, uB1, uA0, uA1);
    STEP(8,  uA0, uA1, uB0, uB1);  STEP(9,  uB0, uB1, uA0, uA1);
    STEP(10, uA0, uA1, uB0, uB1);  STEP(11, uB0, uB1, uA0, uA1);
    STEP(12, uA0, uA1, uB0, uB1);  STEP(13, uB0, uB1, uA0, uA1);
    STEP(14, uA0, uA1, uB0, uB1);  STEP(15, uB0, uB1, uA0, uA1);
    STEP(16, uA0, uA1, uB0, uB1);  STEP(17, uB0, uB1, uA0, uA1);
    #undef STEP
    #undef COMP
    #undef ULOAD
    #undef STAGE

    // ================= routing iterations =================
    // exp-domain logits: e[r] = exp(b[r]); iter 0 is exp(0) = 1 exactly.
    float e[NTILE];
    #pragma unroll
    for (int r = 0; r < NTILE; ++r) e[r] = 1.0f;
    float vv[4];
    const int grp = lane & 7;                // (mq<<1)|bl

    for (int it = 0; it < ITERS; ++it) {
        float esum = 0.0f;
        #pragma unroll
        for (int r = 0; r < NTILE; ++r) esum += e[r];
        esum += __shfl_xor(esum, 8);
        esum += __shfl_xor(esum, 16);
        esum += __shfl_xor(esum, 32);

        float sp0 = 0.f, sp1 = 0.f, sp2 = 0.f, sp3 = 0.f;
        #pragma unroll
        for (int r = 0; r < NTILE; ++r) {
            sp0 = fmaf(e[r], uh[r][0], sp0);
            sp1 = fmaf(e[r], uh[r][1], sp1);
            sp2 = fmaf(e[r], uh[r][2], sp2);
            sp3 = fmaf(e[r], uh[r][3], sp3);
        }
        sp0 += __shfl_xor(sp0, 8);  sp1 += __shfl_xor(sp1, 8);
        sp2 += __shfl_xor(sp2, 8);  sp3 += __shfl_xor(sp3, 8);
        sp0 += __shfl_xor(sp0, 16); sp1 += __shfl_xor(sp1, 16);
        sp2 += __shfl_xor(sp2, 16); sp3 += __shfl_xor(sp3, 16);
        sp0 += __shfl_xor(sp0, 32); sp1 += __shfl_xor(sp1, 32);
        sp2 += __shfl_xor(sp2, 32); sp3 += __shfl_xor(sp3, 32);

        if (lane < 8) {   // one rep per (bl,mq) group
            red_es[wv * 8 + lane] = esum;
            *reinterpret_cast<float4*>(&red_m[(wv * 8 + lane) * 4]) =
                make_float4(sp0, sp1, sp2, sp3);
        }
        __syncthreads();
        float gsum = 0.0f;
        float sa0 = 0.f, sa1 = 0.f, sa2 = 0.f, sa3 = 0.f;
        #pragma unroll
        for (int q = 0; q < NW; ++q) {
            gsum += red_es[q * 8 + grp];
            const float4 rm =
                *reinterpret_cast<const float4*>(&red_m[(q * 8 + grp) * 4]);
            sa0 += rm.x; sa1 += rm.y; sa2 += rm.z; sa3 += rm.w;
        }
        __syncthreads();   // reads done before next iteration's writes

        const float cinv = 1.0f / gsum;
        vv[0] = sa0 * cinv; vv[1] = sa1 * cinv;
        vv[2] = sa2 * cinv; vv[3] = sa3 * cinv;
        float s2 = fmaf(vv[0], vv[0], fmaf(vv[1], vv[1],
                   fmaf(vv[2], vv[2], vv[3] * vv[3])));
        s2 += __shfl_xor(s2, 2);   // combine the 4 m-quarters (same bl)
        s2 += __shfl_xor(s2, 4);
        const float scale = (s2 / (1.0f + s2)) * rsqrtf(s2 + 1e-8f);
        vv[0] *= scale; vv[1] *= scale; vv[2] *= scale; vv[3] *= scale;

        // logit update: a = sum_m v[m]*uh[i][m]; combine mq via masks 2,4
        if (it < ITERS - 1) {
            #pragma unroll
            for (int r = 0; r < NTILE; ++r) {
                float a = fmaf(vv[0], uh[r][0], fmaf(vv[1], uh[r][1],
                          fmaf(vv[2], uh[r][2], vv[3] * uh[r][3])));
                a += __shfl_xor(a, 2);
                a += __shfl_xor(a, 4);
                e[r] *= __expf(a);
            }
        }
    }

    // ---- write v[b0+bl, j, mq*4 .. mq*4+3] ----
    if (tid < 8) {
        float4* op = reinterpret_cast<float4*>(
            out + ((size_t)(b0 + bl) * OUT_CAPS + j) * OUT_D + mq * 4);
        *op = make_float4(vv[0], vv[1], vv[2], vv[3]);
    }
}

extern "C" void kernel_launch(void* const* d_in, const int* in_sizes, int n_in,
                              void* d_out, int out_size, void* d_ws, size_t ws_size,
                              hipStream_t stream) {
    const float* u = (const float*)d_in[0];   // [128, 1152, 8]
    const float* w = (const float*)d_in[1];   // [1152, 32, 8, 16]
    float* out     = (float*)d_out;           // [128, 32, 16]
    (void)in_sizes; (void)n_in; (void)out_size; (void)d_ws; (void)ws_size;

    dim3 grid(OUT_CAPS * (B_SZ / G));   // 32 j x 64 batch-pairs = 2048 blocks
    dim3 block(THREADS);                // 512 threads = 8 waves
    hipLaunchKernelGGL(caps_route, grid, block, 0, stream, u, w, out);
}